// Round 13
// baseline (312.117 us; speedup 1.0000x reference)
//
#include <hip/hip_runtime.h>
#include <hip/hip_bf16.h>

#define H 128
#define NT 4
#define CAP4 40

typedef __attribute__((ext_vector_type(8))) _Float16 half8;
typedef __attribute__((ext_vector_type(8))) unsigned short ushort8;
typedef __attribute__((ext_vector_type(4))) float f32x4;

#if defined(__has_builtin)
#if __has_builtin(__builtin_amdgcn_global_load_lds)
#define HAS_GLL 1
#endif
#endif
#ifndef HAS_GLL
#define HAS_GLL 0
#endif

__device__ __forceinline__ float bf2f(unsigned short u) {
    union { unsigned int i; float f; } v;
    v.i = ((unsigned int)u) << 16;
    return v.f;
}

__device__ __forceinline__ unsigned short f2bf(float f) {
    union { float f; unsigned int i; } v;
    v.f = f;
    unsigned int x = v.i;
    unsigned int r = (x + 0x7fffu + ((x >> 16) & 1u)) >> 16;  // RNE
    return (unsigned short)r;
}

__device__ __forceinline__ float fsigmoid(float x) {
    return 1.0f / (1.0f + __expf(-x));
}
__device__ __forceinline__ float ftanh(float x) {
    return 1.0f - 2.0f / (__expf(2.0f * x) + 1.0f);  // inf-safe both tails
}

// flag-adaptive fp32 read from raw input buffer (1 = bf16-packed, 0 = fp32)
__device__ __forceinline__ float readf(const void* p, long i, int isbf) {
    return isbf ? bf2f(((const unsigned short*)p)[i]) : ((const float*)p)[i];
}

// ---------------------------------------------------------------------------
// async global->LDS 16B (LDS base wave-uniform; HW scatters lane*16B)
// ---------------------------------------------------------------------------
__device__ __forceinline__ void gll16(const _Float16* g, _Float16* l) {
#if HAS_GLL
    __builtin_amdgcn_global_load_lds(
        (const __attribute__((address_space(1))) unsigned int*)g,
        (__attribute__((address_space(3))) unsigned int*)l, 16, 0, 0);
#else
    const int lane = threadIdx.x & 63;
    *(half8*)&l[lane * 8] = *(const half8*)g;
#endif
}

// fragment read honoring the XOR swizzle: chunk g (8 halfs) of row r in a
// [rows][64] LDS tile where LDS[r][p] holds logical chunk (p ^ (r&7)).
__device__ __forceinline__ half8 frag(const _Float16* lds, int r, int g) {
    return *(const half8*)&lds[r * 64 + ((g ^ (r & 7)) * 8)];
}

// ---------------------------------------------------------------------------
// prep_all: consolidated prep kernel. detect_dtype is MERGED: every block
// recomputes the identical 1024-sample flag (cheap, broadcast-cached reads,
// exact same decision function as the old detect kernel); block 0 persists
// it for layer_fused's final-output path. One fewer dependent dispatch.
//   seg 0: states -> h16 (fp16)
//   seg 1: type_W -> BTw FRAG-LINEAR [L][cblk:8][kchunk:64][m:16][j:8]
//   seg 2: gru kernels -> BTg FRAG-LINEAR [L][ncblk:32][kchunk:32][m:16][j:8]
//   seg 3: zero counts4
//   seg 4: biases -> btab/gbsum/gb0c/gb1c
// ---------------------------------------------------------------------------
__global__ void prep_all(
    const void* __restrict__ states, const void* __restrict__ type_W,
    const void* __restrict__ type_b, const void* __restrict__ gk,
    const void* __restrict__ gr, const void* __restrict__ grub,
    _Float16* __restrict__ h16, _Float16* __restrict__ BTw,
    _Float16* __restrict__ BTg, float* __restrict__ btab,
    float* __restrict__ gbsum, float* __restrict__ gb0c,
    float* __restrict__ gb1c, int* __restrict__ counts4,
    int* __restrict__ flag_out,
    long NNH, int nBTw, int nBTg, int NC4, int LAYERS) {
    __shared__ int scnt;
    if (threadIdx.x == 0) scnt = 0;
    __syncthreads();
    {
        const unsigned short* su = (const unsigned short*)states;
        int local = 0;
        for (int t = threadIdx.x; t < 1024; t += 256) {
            unsigned short u = su[2 * t];
            int e = (u >> 7) & 0xFF;
            if (e >= 96 && e <= 158) local++;
        }
        atomicAdd(&scnt, local);
    }
    __syncthreads();
    const int fl = (scnt >= 512) ? 1 : 0;
    if (blockIdx.x == 0 && threadIdx.x == 0) *flag_out = fl;

    long i = (long)blockIdx.x * 256 + threadIdx.x;
    if (i < NNH) {                                  // seg 0
        h16[i] = (_Float16)readf(states, i, fl);
        return;
    }
    i -= NNH;
    if (i < nBTw) {                                 // seg 1 (frag-linear)
        int l = (int)(i >> 16);
        int r16 = (int)(i & 65535);
        int cblk = r16 >> 13;            // 0..7
        int rem = r16 & 8191;
        int g = rem >> 7;                // 0..63 k-chunk
        int mm = (rem >> 3) & 15;
        int j = rem & 7;
        int c = cblk * 16 + mm;          // 0..127
        int k = g * 8 + j;               // 0..511
        int t = k >> 7, kk = k & 127;
        BTw[i] = (_Float16)readf(type_W, (((long)(l * NT + t) * H) + kk) * H + c, fl);
        return;
    }
    i -= nBTw;
    if (i < nBTg) {                                 // seg 2 (frag-linear)
        int l = (int)(i >> 17);
        int r17 = (int)(i & 131071);
        int ncblk = r17 >> 12;           // 0..31
        int rem = r17 & 4095;
        int g = rem >> 7;                // 0..31 k-chunk
        int mm = (rem >> 3) & 15;
        int j = rem & 7;
        int nc = ncblk * 16 + mm;        // 0..511
        int k = g * 8 + j;               // 0..255
        int gblk = nc >> 6, gate = (nc >> 4) & 3;
        int c = gblk * 16 + (nc & 15);
        float v = 0.0f;
        if (gate == 0) {
            v = (k < 128) ? readf(gk, ((long)l * H + k) * 384 + c, fl)
                          : readf(gr, ((long)l * H + (k - 128)) * 384 + c, fl);
        } else if (gate == 1) {
            v = (k < 128) ? readf(gk, ((long)l * H + k) * 384 + 128 + c, fl)
                          : readf(gr, ((long)l * H + (k - 128)) * 384 + 128 + c, fl);
        } else if (gate == 2) {
            if (k < 128) v = readf(gk, ((long)l * H + k) * 384 + 256 + c, fl);
        } else {
            if (k >= 128) v = readf(gr, ((long)l * H + (k - 128)) * 384 + 256 + c, fl);
        }
        BTg[i] = (_Float16)v;
        return;
    }
    i -= nBTg;
    if (i < NC4) {                                  // seg 3
        counts4[i] = 0;
        return;
    }
    i -= NC4;
    {                                               // seg 4 (i < LAYERS*NT*H)
        int j = (int)i;
        if (j < LAYERS * NT * H) btab[j] = readf(type_b, j, fl);
        if (j < LAYERS * 256) {
            int l = j >> 8, c = j & 255;
            gbsum[j] = readf(grub, (long)l * 768 + c, fl) +
                       readf(grub, (long)l * 768 + 384 + c, fl);
        }
        if (j < LAYERS * H) {
            int l = j >> 7, c = j & 127;
            gb0c[j] = readf(grub, (long)l * 768 + 256 + c, fl);
            gb1c[j] = readf(grub, (long)l * 768 + 384 + 256 + c, fl);
        }
    }
}

// ---------------------------------------------------------------------------
// bucket edges by (dst, type); counts4 zeroed by prep_all. counts4[NN][4]
// doubles as the int4 per-row count table for the fused bias epilogue.
// ---------------------------------------------------------------------------
__global__ void place_edges4(const int* __restrict__ edges, int* __restrict__ counts4,
                             int* __restrict__ buckets4, int NE) {
    int e = blockIdx.x * 256 + threadIdx.x;
    if (e >= NE) return;
    int t = edges[3 * e], src = edges[3 * e + 1], dst = edges[3 * e + 2];
    int slot = atomicAdd(&counts4[dst * 4 + t], 1);
    if (slot < CAP4) buckets4[((size_t)dst * 4 + t) * CAP4 + slot] = src;
}

// ---------------------------------------------------------------------------
// gather4 v3: quarter-wave per (node,type) (v1 layout, best measured) with
// the dependent-load chain SHORTENED: the bucket head (first 8 srcs, two
// int4s) is loaded SPECULATIVELY in parallel with the counts4 read (all
// three loads are address-independent -> issued concurrently). Chain drops
// counts->bucket->h16 (3 levels, ~1800cy) to max(counts,bucket)->h16
// (2 levels, ~1200cy). Avg bucket size is 2, so cnt<=8 covers ~99% of
// tasks; rare tails loop over further int4s. h16 loads stay cnt-gated
// (no OOB). Speculative reads of unwritten bucket slots are safe
// (allocated workspace, values discarded).
// ---------------------------------------------------------------------------
__global__ __launch_bounds__(256) void gather4(
    const _Float16* __restrict__ h16, const int* __restrict__ counts4,
    const int* __restrict__ buckets4, _Float16* __restrict__ A4, int NN) {
    int node = blockIdx.x * 4 + (threadIdx.x >> 6);
    int lane = threadIdx.x & 63;
    int q = lane >> 4, i = lane & 15;
    if (node >= NN) return;
    const int* bkt = buckets4 + ((size_t)node * 4 + q) * CAP4;

    int4 b0 = *(const int4*)bkt;          // speculative head (parallel with
    int4 b1 = *(const int4*)(bkt + 4);    //  counts read below)
    int cnt = counts4[node * 4 + q];
    if (cnt > CAP4) cnt = CAP4;

    float acc[8] = {};
    {
        int ss[8] = {b0.x, b0.y, b0.z, b0.w, b1.x, b1.y, b1.z, b1.w};
#pragma unroll
        for (int e = 0; e < 8; e++) {
            if (e < cnt) {
                half8 v = *(const half8*)&h16[(size_t)ss[e] * H + i * 8];
#pragma unroll
                for (int j = 0; j < 8; j++) acc[j] += (float)v[j];
            }
        }
    }
    for (int e = 8; e < cnt; e += 4) {    // rare tail (cnt > 8)
        int4 bb = *(const int4*)(bkt + e);
        int sr[4] = {bb.x, bb.y, bb.z, bb.w};
#pragma unroll
        for (int k = 0; k < 4; k++) {
            if (e + k < cnt) {
                half8 v = *(const half8*)&h16[(size_t)sr[k] * H + i * 8];
#pragma unroll
                for (int j = 0; j < 8; j++) acc[j] += (float)v[j];
            }
        }
    }

    half8 o;
#pragma unroll
    for (int j = 0; j < 8; j++) o[j] = (_Float16)acc[j];
    *(half8*)&A4[((size_t)node * 4 + q) * H + i * 8] = o;
}

// ---------------------------------------------------------------------------
// layer_fused v4 (R6 champion, unchanged): 32-row tiles, per-wave col
// ownership. Phase 1: 16 barrier rounds staging As(32x64 swz) + Bs
// (frag-linear 16KB); wave w owns cols [32w,32w+32). aggL deposit + hL
// stage overlapped; one barrier. Phase 2 barrier-free: wave w = gate-group
// y; B direct from frag-linear BTg (L2-resident); zero-K gate skip.
// Writeout: stride-136 fp16 LDS (aliased over dead Bs), one barrier,
// coalesced 32B/lane hnext stores.
// LDS: As 4K + Bs 16K (alias hout16) + aggL 8K + hL 8K = 36KB -> 4 blk/CU.
// ---------------------------------------------------------------------------
__global__ __launch_bounds__(256, 4) void layer_fused(
    const _Float16* __restrict__ A4,     // [NN][512]
    const _Float16* __restrict__ h16,    // [NN][128]
    const _Float16* __restrict__ BTw,    // frag-linear [8][64][16][8]
    const _Float16* __restrict__ BTg,    // frag-linear [32][32][16][8]
    const float* __restrict__ btab,      // [512]
    const int4* __restrict__ cnt4,       // [NN]
    const float* __restrict__ gbsum,     // [256]
    const float* __restrict__ gb0c,      // [128]
    const float* __restrict__ gb1c,      // [128]
    _Float16* __restrict__ hnext,        // [NN][128]
    void* __restrict__ outbuf,           // final output or nullptr
    const int* __restrict__ flag, int NN) {
    __shared__ __align__(16) _Float16 As[2048];    // 32x64 swizzled
    __shared__ __align__(16) _Float16 Bs[8192];    // frag-linear tile / hout16
    __shared__ __align__(16) _Float16 aggL[4096];  // 2 subtiles 32x64 swz
    __shared__ __align__(16) _Float16 hL[4096];    // 2 subtiles 32x64 swz

    const int row0 = blockIdx.x * 32;
    const int tid = threadIdx.x;
    const int wave = tid >> 6, lane = tid & 63;
    const int m = lane & 15, quad = lane >> 4;

    // ================= phase 1: agg GEMM (K=512) ===========================
    f32x4 acc[2][2] = {};
    for (int kc = 0; kc < 8; kc++) {
        __syncthreads();                 // protect As/Bs while in use
        {                                // stage A 32x64 (swizzled)
            int R = wave * 8;
            int rl = R + (lane >> 3);
            int rg = row0 + rl;
            if (rg >= NN) rg = NN - 1;
            int chunk = (lane & 7) ^ (rl & 7);
            gll16(A4 + (size_t)rg * 512 + kc * 64 + chunk * 8, As + R * 64);
        }
#pragma unroll
        for (int r = 0; r < 4; r++) {    // stage B frag-linear 16KB
            int u = r * 256 + tid;
            int cblk = u >> 7, gp = (u >> 4) & 7, mm = u & 15;
            gll16(BTw + cblk * 8192 + (kc * 8 + gp) * 128 + mm * 8,
                  Bs + (r * 256 + wave * 64) * 8);
        }
        __syncthreads();                 // drain
#pragma unroll
        for (int ks = 0; ks < 2; ks++) {
            half8 a[2], b[2];
#pragma unroll
            for (int mt = 0; mt < 2; mt++)
                a[mt] = frag(As, mt * 16 + m, ks * 4 + quad);
#pragma unroll
            for (int nt = 0; nt < 2; nt++)
                b[nt] = *(const half8*)&Bs[(wave * 2 + nt) * 1024 +
                                           (ks * 4 + quad) * 128 + m * 8];
#pragma unroll
            for (int mt = 0; mt < 2; mt++)
#pragma unroll
                for (int nt = 0; nt < 2; nt++)
                    acc[mt][nt] = __builtin_amdgcn_mfma_f32_16x16x32_f16(
                        a[mt], b[nt], acc[mt][nt], 0, 0, 0);
        }
    }

    {   // stage hL (2 x 32x64 swizzled) -- overlaps aggL deposit below
        int R = wave * 8;
        int rl = R + (lane >> 3);
        int rg = row0 + rl;
        if (rg >= NN) rg = NN - 1;
        int chunk = (lane & 7) ^ (rl & 7);
        gll16(h16 + (size_t)rg * H + chunk * 8, hL + R * 64);
        gll16(h16 + (size_t)rg * H + 64 + chunk * 8, hL + 2048 + R * 64);
    }

    // phase-1 epilogue: +bias, fp16, deposit into aggL (frag-compatible)
#pragma unroll
    for (int mt = 0; mt < 2; mt++) {
#pragma unroll
        for (int i = 0; i < 4; i++) {
            int rl = mt * 16 + quad * 4 + i;
            int rg = row0 + rl;
            if (rg >= NN) rg = NN - 1;
            int4 c4 = cnt4[rg];
#pragma unroll
            for (int nt = 0; nt < 2; nt++) {
                int c = wave * 32 + nt * 16 + m;
                float bias = c4.x * btab[c] + c4.y * btab[128 + c] +
                             c4.z * btab[256 + c] + c4.w * btab[384 + c];
                int sub = c >> 6, cc = c & 63, g = cc >> 3;
                aggL[sub * 2048 + rl * 64 + ((g ^ (rl & 7)) * 8) + (cc & 7)] =
                    (_Float16)(acc[mt][nt][i] + bias);
            }
        }
    }
    __syncthreads();   // drains hL glls + aggL writes; Bs dead -> hout16

    // ================= phase 2: GRU GEMM + gates (barrier-free) ============
    _Float16* hout16 = Bs;               // stride 136 (conflict-free)
    const int fl = outbuf ? *flag : 0;
    const int y = wave;                  // wave owns gate-group y
#pragma unroll
    for (int ch = 0; ch < 2; ch++) {
        f32x4 p[2][4] = {};
        const int ncb0 = y * 8 + ch * 4;
#pragma unroll
        for (int kc = 0; kc < 4; kc++) {
            const int ntA = (kc < 2) ? 2 : 3;   // zero-K gate skip
            const _Float16* Asrc = (kc < 2) ? (aggL + kc * 2048)
                                            : (hL + (kc - 2) * 2048);
#pragma unroll
            for (int ks = 0; ks < 2; ks++) {
                const int gk = kc * 8 + ks * 4 + quad;
                half8 a0 = frag(Asrc, m, ks * 4 + quad);
                half8 a1 = frag(Asrc, 16 + m, ks * 4 + quad);
                half8 b0 = *(const half8*)&BTg[(size_t)(ncb0 + 0) * 4096 +
                                               gk * 128 + m * 8];
                half8 b1 = *(const half8*)&BTg[(size_t)(ncb0 + 1) * 4096 +
                                               gk * 128 + m * 8];
                half8 b2 = *(const half8*)&BTg[(size_t)(ncb0 + ntA) * 4096 +
                                               gk * 128 + m * 8];
                p[0][0] = __builtin_amdgcn_mfma_f32_16x16x32_f16(a0, b0, p[0][0], 0, 0, 0);
                p[1][0] = __builtin_amdgcn_mfma_f32_16x16x32_f16(a1, b0, p[1][0], 0, 0, 0);
                p[0][1] = __builtin_amdgcn_mfma_f32_16x16x32_f16(a0, b1, p[0][1], 0, 0, 0);
                p[1][1] = __builtin_amdgcn_mfma_f32_16x16x32_f16(a1, b1, p[1][1], 0, 0, 0);
                p[0][ntA] = __builtin_amdgcn_mfma_f32_16x16x32_f16(a0, b2, p[0][ntA], 0, 0, 0);
                p[1][ntA] = __builtin_amdgcn_mfma_f32_16x16x32_f16(a1, b2, p[1][ntA], 0, 0, 0);
            }
        }

        // gate epilogue: cols c = (2y+ch)*16 + m
        const int c = (2 * y + ch) * 16 + m;
        const float bz = gbsum[c];
        const float br = gbsum[128 + c];
        const float bx = gb0c[c];
        const float bh = gb1c[c];
        const int sub = c >> 6, cc = c & 63, hg = cc >> 3, hj = cc & 7;
#pragma unroll
        for (int mt = 0; mt < 2; mt++) {
#pragma unroll
            for (int i = 0; i < 4; i++) {
                int rl = mt * 16 + quad * 4 + i;
                int row = row0 + rl;
                float z = fsigmoid(p[mt][0][i] + bz);
                float r = fsigmoid(p[mt][1][i] + br);
                float ccand =
                    ftanh((p[mt][2][i] + bx) + r * (p[mt][3][i] + bh));
                float hv = (float)hL[sub * 2048 + rl * 64 +
                                     ((hg ^ (rl & 7)) * 8) + hj];
                float hn = z * hv + (1.0f - z) * ccand;
                if (outbuf) {
                    if (row < NN) {
                        size_t oi = (size_t)row * H + c;
                        if (fl) ((unsigned short*)outbuf)[oi] = f2bf(hn);
                        else    ((float*)outbuf)[oi] = hn;
                    }
                } else {
                    hout16[rl * 136 + c] = (_Float16)hn;
                }
            }
        }
    }

    // ================= coalesced hnext writeout (non-last layers) ==========
    if (!outbuf) {
        __syncthreads();
        int r = tid >> 3, s = tid & 7;       // row 0..31, 16-col segment
        int row = row0 + r;
        if (row < NN) {
            half8 v0 = *(const half8*)&hout16[r * 136 + s * 16];
            half8 v1 = *(const half8*)&hout16[r * 136 + s * 16 + 8];
            size_t o = (size_t)row * H + s * 16;
            *(half8*)&hnext[o] = v0;
            *(half8*)&hnext[o + 8] = v1;
        }
    }
}

// ---------------------------------------------------------------------------
extern "C" void kernel_launch(void* const* d_in, const int* in_sizes, int n_in,
                              void* d_out, int out_size, void* d_ws, size_t ws_size,
                              hipStream_t stream) {
    const void* states = d_in[0];
    const int*  edges  = (const int*)d_in[1];
    const void* type_W = d_in[2];
    const void* type_b = d_in[3];
    const void* gruk   = d_in[4];
    const void* grur   = d_in[5];
    const void* grub   = d_in[6];

    const int NN = in_sizes[0] / H;    // 50000
    const int NE = in_sizes[1] / 3;    // 400000
    const int nW = in_sizes[2];        // L*NT*128*128
    const int LAYERS = nW / (NT * H * H);

    // --- workspace layout ---
    char* w = (char*)d_ws;
    int* flag = (int*)w;                               w += 64;
    _Float16* h16A  = (_Float16*)w;                    w += (size_t)NN * H * 2;
    _Float16* h16B  = (_Float16*)w;                    w += (size_t)NN * H * 2;
    _Float16* A4    = (_Float16*)w;                    w += (size_t)NN * 4 * H * 2;
    _Float16* BTw = (_Float16*)w;                      w += (size_t)LAYERS * H * 512 * 2;
    _Float16* BTg = (_Float16*)w;                      w += (size_t)LAYERS * 512 * 256 * 2;
    float* btab  = (float*)w;                          w += (size_t)LAYERS * NT * H * 4;
    float* gbsum = (float*)w;                          w += (size_t)LAYERS * 256 * 4;
    float* gb0c  = (float*)w;                          w += (size_t)LAYERS * H * 4;
    float* gb1c  = (float*)w;                          w += (size_t)LAYERS * H * 4;
    int* counts4 = (int*)w;                            w += (size_t)NN * 4 * 4;
    int* buckets4 = (int*)w;                           // [NN][4][CAP4]

    const long NNH = (long)NN * H;
    const int nBTw = LAYERS * 65536;
    const int nBTg = LAYERS * 131072;
    const int NC4 = NN * 4;
    const long ptotal = NNH + nBTw + nBTg + NC4 + LAYERS * NT * H;
    prep_all<<<(int)((ptotal + 255) / 256), 256, 0, stream>>>(
        states, type_W, type_b, gruk, grur, grub,
        h16A, BTw, BTg, btab, gbsum, gb0c, gb1c, counts4, flag,
        NNH, nBTw, nBTg, NC4, LAYERS);

    place_edges4<<<(NE + 255) / 256, 256, 0, stream>>>(edges, counts4, buckets4, NE);

    const int rt32 = (NN + 31) / 32;
    for (int L = 0; L < LAYERS; L++) {
        const _Float16* hcur = (L & 1) ? h16B : h16A;
        _Float16* hnext      = (L & 1) ? h16A : h16B;

        gather4<<<(NN + 3) / 4, 256, 0, stream>>>(hcur, counts4, buckets4, A4, NN);

        layer_fused<<<rt32, 256, 0, stream>>>(
            A4, hcur,
            BTw + (size_t)L * H * 512,
            BTg + (size_t)L * 512 * 256,
            btab + (size_t)L * NT * H, (const int4*)counts4,
            gbsum + (size_t)L * 256, gb0c + (size_t)L * H, gb1c + (size_t)L * H,
            hnext, (L == LAYERS - 1) ? d_out : nullptr, flag, NN);
    }
}

// Round 14
// 254.034 us; speedup vs baseline: 1.2286x; 1.2286x over previous
//
#include <hip/hip_runtime.h>
#include <hip/hip_bf16.h>

#define H 128
#define NT 4
#define CAP4 40

typedef __attribute__((ext_vector_type(8))) _Float16 half8;
typedef __attribute__((ext_vector_type(8))) unsigned short ushort8;
typedef __attribute__((ext_vector_type(4))) float f32x4;

#if defined(__has_builtin)
#if __has_builtin(__builtin_amdgcn_global_load_lds)
#define HAS_GLL 1
#endif
#endif
#ifndef HAS_GLL
#define HAS_GLL 0
#endif

__device__ __forceinline__ float bf2f(unsigned short u) {
    union { unsigned int i; float f; } v;
    v.i = ((unsigned int)u) << 16;
    return v.f;
}

__device__ __forceinline__ unsigned short f2bf(float f) {
    union { float f; unsigned int i; } v;
    v.f = f;
    unsigned int x = v.i;
    unsigned int r = (x + 0x7fffu + ((x >> 16) & 1u)) >> 16;  // RNE
    return (unsigned short)r;
}

__device__ __forceinline__ float fsigmoid(float x) {
    return 1.0f / (1.0f + __expf(-x));
}
__device__ __forceinline__ float ftanh(float x) {
    return 1.0f - 2.0f / (__expf(2.0f * x) + 1.0f);  // inf-safe both tails
}

// flag-adaptive fp32 read from raw input buffer (1 = bf16-packed, 0 = fp32)
__device__ __forceinline__ float readf(const void* p, long i, int isbf) {
    return isbf ? bf2f(((const unsigned short*)p)[i]) : ((const float*)p)[i];
}

// ---------------------------------------------------------------------------
// async global->LDS 16B (LDS base wave-uniform; HW scatters lane*16B)
// ---------------------------------------------------------------------------
__device__ __forceinline__ void gll16(const _Float16* g, _Float16* l) {
#if HAS_GLL
    __builtin_amdgcn_global_load_lds(
        (const __attribute__((address_space(1))) unsigned int*)g,
        (__attribute__((address_space(3))) unsigned int*)l, 16, 0, 0);
#else
    const int lane = threadIdx.x & 63;
    *(half8*)&l[lane * 8] = *(const half8*)g;
#endif
}

// fragment read honoring the XOR swizzle: chunk g (8 halfs) of row r in a
// [rows][64] LDS tile where LDS[r][p] holds logical chunk (p ^ (r&7)).
__device__ __forceinline__ half8 frag(const _Float16* lds, int r, int g) {
    return *(const half8*)&lds[r * 64 + ((g ^ (r & 7)) * 8)];
}

// ---------------------------------------------------------------------------
// dtype detector (separate 1-block kernel -- R13 lesson: merging it into
// prep_all taxed every block ~2x; keep it standalone).
// ---------------------------------------------------------------------------
__global__ void detect_dtype(const unsigned short* __restrict__ states_u16,
                             int* __restrict__ flag) {
    __shared__ int cnt;
    if (threadIdx.x == 0) cnt = 0;
    __syncthreads();
    int local = 0;
    for (int i = threadIdx.x; i < 1024; i += 256) {
        unsigned short u = states_u16[2 * i];
        int e = (u >> 7) & 0xFF;
        if (e >= 96 && e <= 158) local++;
    }
    atomicAdd(&cnt, local);
    __syncthreads();
    if (threadIdx.x == 0) *flag = (cnt >= 512) ? 1 : 0;
}

// ---------------------------------------------------------------------------
// prep_all v2: seg 0 VECTORIZED x8 (R13 counters: prep was scalar-access
// bound at 360 GB/s; seg0 is 94% of threads). Each seg-0 thread converts 8
// contiguous elements: ushort8 (bf16) or 2x f32x4 (fp32) load -> half8
// store. Identical per-element rounding. Grid 26.5k -> ~4.7k blocks.
//   seg 1: type_W -> BTw FRAG-LINEAR [L][cblk:8][kchunk:64][m:16][j:8]
//   seg 2: gru kernels -> BTg FRAG-LINEAR [L][ncblk:32][kchunk:32][m:16][j:8]
//   seg 3: zero counts4
//   seg 4: biases -> btab/gbsum/gb0c/gb1c
// ---------------------------------------------------------------------------
__global__ void prep_all(
    const void* __restrict__ states, const void* __restrict__ type_W,
    const void* __restrict__ type_b, const void* __restrict__ gk,
    const void* __restrict__ gr, const void* __restrict__ grub,
    _Float16* __restrict__ h16, _Float16* __restrict__ BTw,
    _Float16* __restrict__ BTg, float* __restrict__ btab,
    float* __restrict__ gbsum, float* __restrict__ gb0c,
    float* __restrict__ gb1c, int* __restrict__ counts4,
    const int* __restrict__ flag,
    long NNH8, int nBTw, int nBTg, int NC4, int LAYERS) {
    long i = (long)blockIdx.x * 256 + threadIdx.x;
    const int fl = *flag;
    if (i < NNH8) {                                 // seg 0 (x8 vectorized)
        long base = i * 8;
        half8 o;
        if (fl) {
            ushort8 u = *(const ushort8*)((const unsigned short*)states + base);
#pragma unroll
            for (int j = 0; j < 8; j++) o[j] = (_Float16)bf2f(u[j]);
        } else {
            const float* sf = (const float*)states + base;
            f32x4 a = *(const f32x4*)sf;
            f32x4 b = *(const f32x4*)(sf + 4);
#pragma unroll
            for (int j = 0; j < 4; j++) {
                o[j] = (_Float16)a[j];
                o[4 + j] = (_Float16)b[j];
            }
        }
        *(half8*)&h16[base] = o;
        return;
    }
    i -= NNH8;
    if (i < nBTw) {                                 // seg 1 (frag-linear)
        int l = (int)(i >> 16);
        int r16 = (int)(i & 65535);
        int cblk = r16 >> 13;            // 0..7
        int rem = r16 & 8191;
        int g = rem >> 7;                // 0..63 k-chunk
        int mm = (rem >> 3) & 15;
        int j = rem & 7;
        int c = cblk * 16 + mm;          // 0..127
        int k = g * 8 + j;               // 0..511
        int t = k >> 7, kk = k & 127;
        BTw[i] = (_Float16)readf(type_W, (((long)(l * NT + t) * H) + kk) * H + c, fl);
        return;
    }
    i -= nBTw;
    if (i < nBTg) {                                 // seg 2 (frag-linear)
        int l = (int)(i >> 17);
        int r17 = (int)(i & 131071);
        int ncblk = r17 >> 12;           // 0..31
        int rem = r17 & 4095;
        int g = rem >> 7;                // 0..31 k-chunk
        int mm = (rem >> 3) & 15;
        int j = rem & 7;
        int nc = ncblk * 16 + mm;        // 0..511
        int k = g * 8 + j;               // 0..255
        int gblk = nc >> 6, gate = (nc >> 4) & 3;
        int c = gblk * 16 + (nc & 15);
        float v = 0.0f;
        if (gate == 0) {
            v = (k < 128) ? readf(gk, ((long)l * H + k) * 384 + c, fl)
                          : readf(gr, ((long)l * H + (k - 128)) * 384 + c, fl);
        } else if (gate == 1) {
            v = (k < 128) ? readf(gk, ((long)l * H + k) * 384 + 128 + c, fl)
                          : readf(gr, ((long)l * H + (k - 128)) * 384 + 128 + c, fl);
        } else if (gate == 2) {
            if (k < 128) v = readf(gk, ((long)l * H + k) * 384 + 256 + c, fl);
        } else {
            if (k >= 128) v = readf(gr, ((long)l * H + (k - 128)) * 384 + 256 + c, fl);
        }
        BTg[i] = (_Float16)v;
        return;
    }
    i -= nBTg;
    if (i < NC4) {                                  // seg 3
        counts4[i] = 0;
        return;
    }
    i -= NC4;
    {                                               // seg 4 (i < LAYERS*NT*H)
        int j = (int)i;
        if (j < LAYERS * NT * H) btab[j] = readf(type_b, j, fl);
        if (j < LAYERS * 256) {
            int l = j >> 8, c = j & 255;
            gbsum[j] = readf(grub, (long)l * 768 + c, fl) +
                       readf(grub, (long)l * 768 + 384 + c, fl);
        }
        if (j < LAYERS * H) {
            int l = j >> 7, c = j & 127;
            gb0c[j] = readf(grub, (long)l * 768 + 256 + c, fl);
            gb1c[j] = readf(grub, (long)l * 768 + 384 + 256 + c, fl);
        }
    }
}

// ---------------------------------------------------------------------------
// bucket edges by (dst, type); counts4 zeroed by prep_all. counts4[NN][4]
// doubles as the int4 per-row count table for the fused bias epilogue.
// ---------------------------------------------------------------------------
__global__ void place_edges4(const int* __restrict__ edges, int* __restrict__ counts4,
                             int* __restrict__ buckets4, int NE) {
    int e = blockIdx.x * 256 + threadIdx.x;
    if (e >= NE) return;
    int t = edges[3 * e], src = edges[3 * e + 1], dst = edges[3 * e + 2];
    int slot = atomicAdd(&counts4[dst * 4 + t], 1);
    if (slot < CAP4) buckets4[((size_t)dst * 4 + t) * CAP4 + slot] = src;
}

// ---------------------------------------------------------------------------
// gather4 (R6 champion v1): one wave per node; quarter-wave q owns type-q's
// edge list. Lane i of group q reads h16[src][i*8..i*8+8) (16 lanes x 16B
// = one row). Unroll-4 for loads in flight. R12/R13 falsified both the
// full-wave variant (task setup overhead dominates at avg cnt=2) and the
// speculative-head variant (guarded 8-slot unroll costs more than the
// dependence level it removes). This layout is the measured optimum.
// ---------------------------------------------------------------------------
__global__ __launch_bounds__(256) void gather4(
    const _Float16* __restrict__ h16, const int* __restrict__ counts4,
    const int* __restrict__ buckets4, _Float16* __restrict__ A4, int NN) {
    int node = blockIdx.x * 4 + (threadIdx.x >> 6);
    int lane = threadIdx.x & 63;
    int q = lane >> 4, i = lane & 15;
    if (node >= NN) return;
    int cnt = counts4[node * 4 + q];
    if (cnt > CAP4) cnt = CAP4;
    const int* bkt = buckets4 + ((size_t)node * 4 + q) * CAP4;

    float acc[8] = {};
    int e = 0;
    for (; e + 4 <= cnt; e += 4) {
        int s0 = bkt[e], s1 = bkt[e + 1], s2 = bkt[e + 2], s3 = bkt[e + 3];
        half8 v0 = *(const half8*)&h16[(size_t)s0 * H + i * 8];
        half8 v1 = *(const half8*)&h16[(size_t)s1 * H + i * 8];
        half8 v2 = *(const half8*)&h16[(size_t)s2 * H + i * 8];
        half8 v3 = *(const half8*)&h16[(size_t)s3 * H + i * 8];
#pragma unroll
        for (int j = 0; j < 8; j++)
            acc[j] += ((float)v0[j] + (float)v1[j]) + ((float)v2[j] + (float)v3[j]);
    }
    if (e + 2 <= cnt) {
        int s0 = bkt[e], s1 = bkt[e + 1];
        half8 v0 = *(const half8*)&h16[(size_t)s0 * H + i * 8];
        half8 v1 = *(const half8*)&h16[(size_t)s1 * H + i * 8];
#pragma unroll
        for (int j = 0; j < 8; j++) acc[j] += (float)v0[j] + (float)v1[j];
        e += 2;
    }
    if (e < cnt) {
        int s0 = bkt[e];
        half8 v0 = *(const half8*)&h16[(size_t)s0 * H + i * 8];
#pragma unroll
        for (int j = 0; j < 8; j++) acc[j] += (float)v0[j];
    }

    half8 o;
#pragma unroll
    for (int j = 0; j < 8; j++) o[j] = (_Float16)acc[j];
    *(half8*)&A4[((size_t)node * 4 + q) * H + i * 8] = o;
}

// ---------------------------------------------------------------------------
// layer_fused v4 (R6 champion, unchanged): 32-row tiles, per-wave col
// ownership. Phase 1: 16 barrier rounds staging As(32x64 swz) + Bs
// (frag-linear 16KB); wave w owns cols [32w,32w+32). aggL deposit + hL
// stage overlapped; one barrier. Phase 2 barrier-free: wave w = gate-group
// y; B direct from frag-linear BTg (L2-resident); zero-K gate skip.
// Writeout: stride-136 fp16 LDS (aliased over dead Bs), one barrier,
// coalesced 32B/lane hnext stores.
// LDS: As 4K + Bs 16K (alias hout16) + aggL 8K + hL 8K = 36KB -> 4 blk/CU.
// ---------------------------------------------------------------------------
__global__ __launch_bounds__(256, 4) void layer_fused(
    const _Float16* __restrict__ A4,     // [NN][512]
    const _Float16* __restrict__ h16,    // [NN][128]
    const _Float16* __restrict__ BTw,    // frag-linear [8][64][16][8]
    const _Float16* __restrict__ BTg,    // frag-linear [32][32][16][8]
    const float* __restrict__ btab,      // [512]
    const int4* __restrict__ cnt4,       // [NN]
    const float* __restrict__ gbsum,     // [256]
    const float* __restrict__ gb0c,      // [128]
    const float* __restrict__ gb1c,      // [128]
    _Float16* __restrict__ hnext,        // [NN][128]
    void* __restrict__ outbuf,           // final output or nullptr
    const int* __restrict__ flag, int NN) {
    __shared__ __align__(16) _Float16 As[2048];    // 32x64 swizzled
    __shared__ __align__(16) _Float16 Bs[8192];    // frag-linear tile / hout16
    __shared__ __align__(16) _Float16 aggL[4096];  // 2 subtiles 32x64 swz
    __shared__ __align__(16) _Float16 hL[4096];    // 2 subtiles 32x64 swz

    const int row0 = blockIdx.x * 32;
    const int tid = threadIdx.x;
    const int wave = tid >> 6, lane = tid & 63;
    const int m = lane & 15, quad = lane >> 4;

    // ================= phase 1: agg GEMM (K=512) ===========================
    f32x4 acc[2][2] = {};
    for (int kc = 0; kc < 8; kc++) {
        __syncthreads();                 // protect As/Bs while in use
        {                                // stage A 32x64 (swizzled)
            int R = wave * 8;
            int rl = R + (lane >> 3);
            int rg = row0 + rl;
            if (rg >= NN) rg = NN - 1;
            int chunk = (lane & 7) ^ (rl & 7);
            gll16(A4 + (size_t)rg * 512 + kc * 64 + chunk * 8, As + R * 64);
        }
#pragma unroll
        for (int r = 0; r < 4; r++) {    // stage B frag-linear 16KB
            int u = r * 256 + tid;
            int cblk = u >> 7, gp = (u >> 4) & 7, mm = u & 15;
            gll16(BTw + cblk * 8192 + (kc * 8 + gp) * 128 + mm * 8,
                  Bs + (r * 256 + wave * 64) * 8);
        }
        __syncthreads();                 // drain
#pragma unroll
        for (int ks = 0; ks < 2; ks++) {
            half8 a[2], b[2];
#pragma unroll
            for (int mt = 0; mt < 2; mt++)
                a[mt] = frag(As, mt * 16 + m, ks * 4 + quad);
#pragma unroll
            for (int nt = 0; nt < 2; nt++)
                b[nt] = *(const half8*)&Bs[(wave * 2 + nt) * 1024 +
                                           (ks * 4 + quad) * 128 + m * 8];
#pragma unroll
            for (int mt = 0; mt < 2; mt++)
#pragma unroll
                for (int nt = 0; nt < 2; nt++)
                    acc[mt][nt] = __builtin_amdgcn_mfma_f32_16x16x32_f16(
                        a[mt], b[nt], acc[mt][nt], 0, 0, 0);
        }
    }

    {   // stage hL (2 x 32x64 swizzled) -- overlaps aggL deposit below
        int R = wave * 8;
        int rl = R + (lane >> 3);
        int rg = row0 + rl;
        if (rg >= NN) rg = NN - 1;
        int chunk = (lane & 7) ^ (rl & 7);
        gll16(h16 + (size_t)rg * H + chunk * 8, hL + R * 64);
        gll16(h16 + (size_t)rg * H + 64 + chunk * 8, hL + 2048 + R * 64);
    }

    // phase-1 epilogue: +bias, fp16, deposit into aggL (frag-compatible)
#pragma unroll
    for (int mt = 0; mt < 2; mt++) {
#pragma unroll
        for (int i = 0; i < 4; i++) {
            int rl = mt * 16 + quad * 4 + i;
            int rg = row0 + rl;
            if (rg >= NN) rg = NN - 1;
            int4 c4 = cnt4[rg];
#pragma unroll
            for (int nt = 0; nt < 2; nt++) {
                int c = wave * 32 + nt * 16 + m;
                float bias = c4.x * btab[c] + c4.y * btab[128 + c] +
                             c4.z * btab[256 + c] + c4.w * btab[384 + c];
                int sub = c >> 6, cc = c & 63, g = cc >> 3;
                aggL[sub * 2048 + rl * 64 + ((g ^ (rl & 7)) * 8) + (cc & 7)] =
                    (_Float16)(acc[mt][nt][i] + bias);
            }
        }
    }
    __syncthreads();   // drains hL glls + aggL writes; Bs dead -> hout16

    // ================= phase 2: GRU GEMM + gates (barrier-free) ============
    _Float16* hout16 = Bs;               // stride 136 (conflict-free)
    const int fl = outbuf ? *flag : 0;
    const int y = wave;                  // wave owns gate-group y
#pragma unroll
    for (int ch = 0; ch < 2; ch++) {
        f32x4 p[2][4] = {};
        const int ncb0 = y * 8 + ch * 4;
#pragma unroll
        for (int kc = 0; kc < 4; kc++) {
            const int ntA = (kc < 2) ? 2 : 3;   // zero-K gate skip
            const _Float16* Asrc = (kc < 2) ? (aggL + kc * 2048)
                                            : (hL + (kc - 2) * 2048);
#pragma unroll
            for (int ks = 0; ks < 2; ks++) {
                const int gk = kc * 8 + ks * 4 + quad;
                half8 a0 = frag(Asrc, m, ks * 4 + quad);
                half8 a1 = frag(Asrc, 16 + m, ks * 4 + quad);
                half8 b0 = *(const half8*)&BTg[(size_t)(ncb0 + 0) * 4096 +
                                               gk * 128 + m * 8];
                half8 b1 = *(const half8*)&BTg[(size_t)(ncb0 + 1) * 4096 +
                                               gk * 128 + m * 8];
                half8 b2 = *(const half8*)&BTg[(size_t)(ncb0 + ntA) * 4096 +
                                               gk * 128 + m * 8];
                p[0][0] = __builtin_amdgcn_mfma_f32_16x16x32_f16(a0, b0, p[0][0], 0, 0, 0);
                p[1][0] = __builtin_amdgcn_mfma_f32_16x16x32_f16(a1, b0, p[1][0], 0, 0, 0);
                p[0][1] = __builtin_amdgcn_mfma_f32_16x16x32_f16(a0, b1, p[0][1], 0, 0, 0);
                p[1][1] = __builtin_amdgcn_mfma_f32_16x16x32_f16(a1, b1, p[1][1], 0, 0, 0);
                p[0][ntA] = __builtin_amdgcn_mfma_f32_16x16x32_f16(a0, b2, p[0][ntA], 0, 0, 0);
                p[1][ntA] = __builtin_amdgcn_mfma_f32_16x16x32_f16(a1, b2, p[1][ntA], 0, 0, 0);
            }
        }

        // gate epilogue: cols c = (2y+ch)*16 + m
        const int c = (2 * y + ch) * 16 + m;
        const float bz = gbsum[c];
        const float br = gbsum[128 + c];
        const float bx = gb0c[c];
        const float bh = gb1c[c];
        const int sub = c >> 6, cc = c & 63, hg = cc >> 3, hj = cc & 7;
#pragma unroll
        for (int mt = 0; mt < 2; mt++) {
#pragma unroll
            for (int i = 0; i < 4; i++) {
                int rl = mt * 16 + quad * 4 + i;
                int row = row0 + rl;
                float z = fsigmoid(p[mt][0][i] + bz);
                float r = fsigmoid(p[mt][1][i] + br);
                float ccand =
                    ftanh((p[mt][2][i] + bx) + r * (p[mt][3][i] + bh));
                float hv = (float)hL[sub * 2048 + rl * 64 +
                                     ((hg ^ (rl & 7)) * 8) + hj];
                float hn = z * hv + (1.0f - z) * ccand;
                if (outbuf) {
                    if (row < NN) {
                        size_t oi = (size_t)row * H + c;
                        if (fl) ((unsigned short*)outbuf)[oi] = f2bf(hn);
                        else    ((float*)outbuf)[oi] = hn;
                    }
                } else {
                    hout16[rl * 136 + c] = (_Float16)hn;
                }
            }
        }
    }

    // ================= coalesced hnext writeout (non-last layers) ==========
    if (!outbuf) {
        __syncthreads();
        int r = tid >> 3, s = tid & 7;       // row 0..31, 16-col segment
        int row = row0 + r;
        if (row < NN) {
            half8 v0 = *(const half8*)&hout16[r * 136 + s * 16];
            half8 v1 = *(const half8*)&hout16[r * 136 + s * 16 + 8];
            size_t o = (size_t)row * H + s * 16;
            *(half8*)&hnext[o] = v0;
            *(half8*)&hnext[o + 8] = v1;
        }
    }
}

// ---------------------------------------------------------------------------
extern "C" void kernel_launch(void* const* d_in, const int* in_sizes, int n_in,
                              void* d_out, int out_size, void* d_ws, size_t ws_size,
                              hipStream_t stream) {
    const void* states = d_in[0];
    const int*  edges  = (const int*)d_in[1];
    const void* type_W = d_in[2];
    const void* type_b = d_in[3];
    const void* gruk   = d_in[4];
    const void* grur   = d_in[5];
    const void* grub   = d_in[6];

    const int NN = in_sizes[0] / H;    // 50000
    const int NE = in_sizes[1] / 3;    // 400000
    const int nW = in_sizes[2];        // L*NT*128*128
    const int LAYERS = nW / (NT * H * H);

    // --- workspace layout ---
    char* w = (char*)d_ws;
    int* flag = (int*)w;                               w += 64;
    _Float16* h16A  = (_Float16*)w;                    w += (size_t)NN * H * 2;
    _Float16* h16B  = (_Float16*)w;                    w += (size_t)NN * H * 2;
    _Float16* A4    = (_Float16*)w;                    w += (size_t)NN * 4 * H * 2;
    _Float16* BTw = (_Float16*)w;                      w += (size_t)LAYERS * H * 512 * 2;
    _Float16* BTg = (_Float16*)w;                      w += (size_t)LAYERS * 512 * 256 * 2;
    float* btab  = (float*)w;                          w += (size_t)LAYERS * NT * H * 4;
    float* gbsum = (float*)w;                          w += (size_t)LAYERS * 256 * 4;
    float* gb0c  = (float*)w;                          w += (size_t)LAYERS * H * 4;
    float* gb1c  = (float*)w;                          w += (size_t)LAYERS * H * 4;
    int* counts4 = (int*)w;                            w += (size_t)NN * 4 * 4;
    int* buckets4 = (int*)w;                           // [NN][4][CAP4]

    detect_dtype<<<1, 256, 0, stream>>>((const unsigned short*)states, flag);

    const long NNH8 = (long)NN * H / 8;
    const int nBTw = LAYERS * 65536;
    const int nBTg = LAYERS * 131072;
    const int NC4 = NN * 4;
    const long ptotal = NNH8 + nBTw + nBTg + NC4 + LAYERS * NT * H;
    prep_all<<<(int)((ptotal + 255) / 256), 256, 0, stream>>>(
        states, type_W, type_b, gruk, grur, grub,
        h16A, BTw, BTg, btab, gbsum, gb0c, gb1c, counts4, flag,
        NNH8, nBTw, nBTg, NC4, LAYERS);

    place_edges4<<<(NE + 255) / 256, 256, 0, stream>>>(edges, counts4, buckets4, NE);

    const int rt32 = (NN + 31) / 32;
    for (int L = 0; L < LAYERS; L++) {
        const _Float16* hcur = (L & 1) ? h16B : h16A;
        _Float16* hnext      = (L & 1) ? h16A : h16B;

        gather4<<<(NN + 3) / 4, 256, 0, stream>>>(hcur, counts4, buckets4, A4, NN);

        layer_fused<<<rt32, 256, 0, stream>>>(
            A4, hcur,
            BTw + (size_t)L * H * 512,
            BTg + (size_t)L * 512 * 256,
            btab + (size_t)L * NT * H, (const int4*)counts4,
            gbsum + (size_t)L * 256, gb0c + (size_t)L * H, gb1c + (size_t)L * H,
            hnext, (L == LAYERS - 1) ? d_out : nullptr, flag, NN);
    }
}